// Round 18
// baseline (22.434 us; speedup 1.0000x reference)
//
#include <hip/hip_runtime.h>
#include <hip/hip_bf16.h>

#define DD 256
#define NROWS 16384

typedef float f32x4 __attribute__((ext_vector_type(4)));
typedef __bf16 bf16x4 __attribute__((ext_vector_type(4)));
typedef __bf16 bf16x8 __attribute__((ext_vector_type(8)));

__device__ __forceinline__ bf16x8 cvt8(f32x4 lo, f32x4 hi) {
  bf16x8 v;
#pragma unroll
  for (int j = 0; j < 4; ++j) {
    v[j] = (__bf16)lo[j];
    v[4 + j] = (__bf16)hi[j];
  }
  return v;
}

// ---------------------------------------------------------------------------
// K1: Wc = Wout @ Wv (bf16), bc = bout + Wout @ bv.  [R13 version VERBATIM;
// measured D1 = 4.3us. Do not touch blind (R16 lesson).]
// ---------------------------------------------------------------------------
__global__ __launch_bounds__(1024) void wc_bc_kernel(
    const float* __restrict__ Wqkv, const float* __restrict__ bqkv,
    const float* __restrict__ Wout, const float* __restrict__ bout,
    __bf16* __restrict__ Wc, float* __restrict__ bc) {
  __shared__ f32x4 part[16][64];
  __shared__ float red[4];
  const int i = blockIdx.x;
  const int t = threadIdx.x;
  const int w = t >> 6, l = t & 63;
  const float* __restrict__ Wv = Wqkv + 2 * DD * DD;
  const float* __restrict__ bv = bqkv + 2 * DD;
  const float* __restrict__ wrow = Wout + (size_t)i * DD;

  f32x4 wr[4];
#pragma unroll
  for (int k = 0; k < 4; ++k) wr[k] = *(const f32x4*)(wrow + w * 16 + k * 4);

  const float* wvp = Wv + (size_t)(w * 16) * DD + l * 4;
  f32x4 a0 = {0.f, 0.f, 0.f, 0.f}, a1 = {0.f, 0.f, 0.f, 0.f};
  f32x4 a2 = {0.f, 0.f, 0.f, 0.f}, a3 = {0.f, 0.f, 0.f, 0.f};
#pragma unroll
  for (int k = 0; k < 4; ++k) {
    a0 += wr[k][0] * *(const f32x4*)(wvp + (size_t)(4 * k + 0) * DD);
    a1 += wr[k][1] * *(const f32x4*)(wvp + (size_t)(4 * k + 1) * DD);
    a2 += wr[k][2] * *(const f32x4*)(wvp + (size_t)(4 * k + 2) * DD);
    a3 += wr[k][3] * *(const f32x4*)(wvp + (size_t)(4 * k + 3) * DD);
  }
  part[w][l] = (a0 + a1) + (a2 + a3);

  if (t < 256) {
    float p = wrow[t] * bv[t];
#pragma unroll
    for (int off = 32; off > 0; off >>= 1) p += __shfl_down(p, off);
    if (l == 0) red[w] = p;
  }
  __syncthreads();
  if (w == 0) {
    f32x4 s = {0.f, 0.f, 0.f, 0.f};
#pragma unroll
    for (int k = 0; k < 16; ++k) s += part[k][l];
    bf16x4 o;
#pragma unroll
    for (int j = 0; j < 4; ++j) o[j] = (__bf16)s[j];
    *(bf16x4*)(Wc + (size_t)i * DD + l * 4) = o;
    if (l == 0) bc[i] = bout[i] + red[0] + red[1] + red[2] + red[3];
  }
}

// ---------------------------------------------------------------------------
// K2: out = x + x @ Wc^T + bc.  ONE-barrier 8-wave full-width blocks:
// 512 thr = 8 waves; block = 32 rows x 256 cols; wave w owns cols [32w,+32)
// (2 col-tiles -> af[2][8] = 64 VGPR, half of R17 -> 4 waves/SIMD under
// launch_bounds(512,4)). All 32 rows staged once into 16KB LDS, ONE
// __syncthreads, then pure {ds_read + MFMA + store} (R13/R17 had 2-8
// barriers/block -- the measured latency chain). af loads issue pre-barrier
// (overlap staging). Residual from LDS bf16 (R17-validated). Grid 512.
// ---------------------------------------------------------------------------
__global__ __launch_bounds__(512, 4) void knn_attn_main(
    const float* __restrict__ x, const __bf16* __restrict__ Wc,
    const float* __restrict__ bc, float* __restrict__ out) {
  __shared__ __bf16 xs[32 * DD];  // 16 KiB, single buffer, swizzled

  const int t = threadIdx.x;
  const int w = t >> 6, l = t & 63;  // 8 waves
  const int Rbase = blockIdx.x * 32;

  const int xrow = l & 15, g4 = l >> 4;
  const int rsw = (xrow & 7) << 4;

  // Weight fragments for this wave's 2 col-tiles (global, L2-hot) + bias.
  // Issued before the barrier so they fly under the x staging latency.
  bf16x8 af[2][8];
  f32x4 bias[2];
#pragma unroll
  for (int ct = 0; ct < 2; ++ct) {
    const __bf16* wrp = Wc + (size_t)(w * 32 + ct * 16 + xrow) * DD + g4 * 8;
#pragma unroll
    for (int ks = 0; ks < 8; ++ks) af[ct][ks] = *(const bf16x8*)(wrp + ks * 32);
    bias[ct] = *(const f32x4*)(bc + w * 32 + ct * 16 + g4 * 4);  // incl. bout
  }

  // Stage all 32 rows: thread t -> row sr = t>>4, 16 floats at seg sc = t&15.
  {
    const int sr = t >> 4, sc = t & 15;
    const int ssw = (sr & 7) << 4;
    const int sbase = sr * 512 + sc * 32;
    const float* s0 = x + (size_t)(Rbase + sr) * DD + sc * 16;
    f32x4 a = *(const f32x4*)(s0 + 0);
    f32x4 b = *(const f32x4*)(s0 + 4);
    f32x4 c = *(const f32x4*)(s0 + 8);
    f32x4 d = *(const f32x4*)(s0 + 12);
    *(bf16x8*)((char*)xs + ((sbase + 0) ^ ssw)) = cvt8(a, b);
    *(bf16x8*)((char*)xs + ((sbase + 16) ^ ssw)) = cvt8(c, d);
  }
  __syncthreads();  // the ONLY barrier

#pragma unroll
  for (int i = 0; i < 2; ++i) {  // two 16-row tiles
    const int lrow = i * 16 + xrow;  // LDS row; (lrow&7)==(xrow&7) -> rsw ok
    // x fragments read once per tile, shared by both col-tiles.
    bf16x8 xf[8];
#pragma unroll
    for (int ks = 0; ks < 8; ++ks)
      xf[ks] = *(const bf16x8*)((const char*)xs +
                                ((lrow * 512 + ks * 64 + g4 * 16) ^ rsw));

#pragma unroll
    for (int ct = 0; ct < 2; ++ct) {
      f32x4 acc = {0.f, 0.f, 0.f, 0.f};
#pragma unroll
      for (int ks = 0; ks < 8; ++ks)
        acc = __builtin_amdgcn_mfma_f32_16x16x32_bf16(af[ct][ks], xf[ks], acc, 0, 0, 0);
      // epilogue: D col(l&15)=x-row, rowquad g4*4+reg = out-col (verified).
      const int ocol = w * 32 + ct * 16 + g4 * 4;
      bf16x4 xr4 = *(const bf16x4*)((const char*)xs +
                                    ((lrow * 512 + ocol * 2) ^ rsw));
      f32x4 xres;
#pragma unroll
      for (int j = 0; j < 4; ++j) xres[j] = (float)xr4[j];
      *(f32x4*)(out + (size_t)(Rbase + i * 16 + xrow) * DD + ocol) =
          acc + xres + bias[ct];
    }
  }
}

extern "C" void kernel_launch(void* const* d_in, const int* in_sizes, int n_in,
                              void* d_out, int out_size, void* d_ws, size_t ws_size,
                              hipStream_t stream) {
  const float* x = (const float*)d_in[0];
  const float* Wqkv = (const float*)d_in[1];
  const float* bqkv = (const float*)d_in[2];
  const float* Wout = (const float*)d_in[3];
  const float* bout = (const float*)d_in[4];
  float* out = (float*)d_out;

  __bf16* Wc = (__bf16*)d_ws;                                   // 128 KiB
  float* bc = (float*)((char*)d_ws + DD * DD * sizeof(__bf16)); // +1 KiB

  wc_bc_kernel<<<DD, 1024, 0, stream>>>(Wqkv, bqkv, Wout, bout, Wc, bc);
  knn_attn_main<<<NROWS / 32, 512, 0, stream>>>(x, Wc, bc, out);
}

// Round 19
// 22.354 us; speedup vs baseline: 1.0036x; 1.0036x over previous
//
#include <hip/hip_runtime.h>
#include <hip/hip_bf16.h>

#define DD 256
#define NROWS 16384

typedef float f32x4 __attribute__((ext_vector_type(4)));
typedef __bf16 bf16x4 __attribute__((ext_vector_type(4)));
typedef __bf16 bf16x8 __attribute__((ext_vector_type(8)));

__device__ __forceinline__ bf16x8 cvt8(f32x4 lo, f32x4 hi) {
  bf16x8 v;
#pragma unroll
  for (int j = 0; j < 4; ++j) {
    v[j] = (__bf16)lo[j];
    v[4 + j] = (__bf16)hi[j];
  }
  return v;
}

// ---------------------------------------------------------------------------
// K1: Wc = Wout @ Wv (bf16), bc = bout + Wout @ bv.
// TRAFFIC FIX (measured D1=4.3us ~= 64MB L3 / 14TB/s): R13's 256 blocks each
// read the FULL 256KB Wv. Now block = 4 rows x 64 cols -> per-block Wv slice
// 64KB -> aggregate 16MB (4x less). 256 blocks x 1024 thr = full machine,
// 4 waves/SIMD. Wave w owns j-slice [16w,+16); lane l owns col c0+l; Wout
// coeffs wave-uniform (s_load); 16KB LDS partial reduce. bc in qc==0 blocks.
// ---------------------------------------------------------------------------
__global__ __launch_bounds__(1024) void wc_bc_kernel(
    const float* __restrict__ Wqkv, const float* __restrict__ bqkv,
    const float* __restrict__ Wout, const float* __restrict__ bout,
    __bf16* __restrict__ Wc, float* __restrict__ bc) {
  __shared__ float part[16][4][64];  // 16 KiB
  __shared__ float red[4];
  const int b = blockIdx.x;
  const int i0 = (b >> 2) * 4;  // 4 Wc rows
  const int qc = b & 3;         // column group
  const int c0 = qc * 64;
  const int t = threadIdx.x;
  const int w = t >> 6, l = t & 63;  // 16 waves
  const float* __restrict__ Wv = Wqkv + 2 * DD * DD;
  const float* __restrict__ bv = bqkv + 2 * DD;

  // wave-uniform Wout coefficients: 4 rows x 16 j's (scalar loads)
  float wo[4][16];
#pragma unroll
  for (int r = 0; r < 4; ++r)
#pragma unroll
    for (int jj = 0; jj < 16; ++jj)
      wo[r][jj] = Wout[(size_t)(i0 + r) * DD + w * 16 + jj];

  // 16 independent coalesced loads (256B/wave), 4 accum rows
  float acc0 = 0.f, acc1 = 0.f, acc2 = 0.f, acc3 = 0.f;
  const float* wvp = Wv + (size_t)(w * 16) * DD + c0 + l;
#pragma unroll
  for (int jj = 0; jj < 16; ++jj) {
    const float wv = wvp[(size_t)jj * DD];
    acc0 += wo[0][jj] * wv;
    acc1 += wo[1][jj] * wv;
    acc2 += wo[2][jj] * wv;
    acc3 += wo[3][jj] * wv;
  }
  part[w][0][l] = acc0;
  part[w][1][l] = acc1;
  part[w][2][l] = acc2;
  part[w][3][l] = acc3;

  if (qc == 0 && t < 256) {  // bc partials (waves 0-3)
    const int r = t >> 6, ll = t & 63;
    float p = 0.f;
#pragma unroll
    for (int k = 0; k < 4; ++k)
      p += Wout[(size_t)(i0 + r) * DD + k * 64 + ll] * bv[k * 64 + ll];
#pragma unroll
    for (int off = 32; off > 0; off >>= 1) p += __shfl_down(p, off);
    if (ll == 0) red[r] = p;
  }
  __syncthreads();
  if (t < 256) {
    const int r = t >> 6, ll = t & 63;
    float s = 0.f;
#pragma unroll
    for (int k = 0; k < 16; ++k) s += part[k][r][ll];
    Wc[(size_t)(i0 + r) * DD + c0 + ll] = (__bf16)s;
    if (qc == 0 && ll == 0) bc[i0 + r] = bout[i0 + r] + red[r];
  }
}

// ---------------------------------------------------------------------------
// K2: out = x + x @ Wc^T + bc.  [R18 version VERBATIM -- best-tied; kept
// unchanged this round to isolate the K1 variable.]
// ---------------------------------------------------------------------------
__global__ __launch_bounds__(512, 4) void knn_attn_main(
    const float* __restrict__ x, const __bf16* __restrict__ Wc,
    const float* __restrict__ bc, float* __restrict__ out) {
  __shared__ __bf16 xs[32 * DD];  // 16 KiB, single buffer, swizzled

  const int t = threadIdx.x;
  const int w = t >> 6, l = t & 63;  // 8 waves
  const int Rbase = blockIdx.x * 32;

  const int xrow = l & 15, g4 = l >> 4;
  const int rsw = (xrow & 7) << 4;

  bf16x8 af[2][8];
  f32x4 bias[2];
#pragma unroll
  for (int ct = 0; ct < 2; ++ct) {
    const __bf16* wrp = Wc + (size_t)(w * 32 + ct * 16 + xrow) * DD + g4 * 8;
#pragma unroll
    for (int ks = 0; ks < 8; ++ks) af[ct][ks] = *(const bf16x8*)(wrp + ks * 32);
    bias[ct] = *(const f32x4*)(bc + w * 32 + ct * 16 + g4 * 4);
  }

  {
    const int sr = t >> 4, sc = t & 15;
    const int ssw = (sr & 7) << 4;
    const int sbase = sr * 512 + sc * 32;
    const float* s0 = x + (size_t)(Rbase + sr) * DD + sc * 16;
    f32x4 a = *(const f32x4*)(s0 + 0);
    f32x4 b = *(const f32x4*)(s0 + 4);
    f32x4 c = *(const f32x4*)(s0 + 8);
    f32x4 d = *(const f32x4*)(s0 + 12);
    *(bf16x8*)((char*)xs + ((sbase + 0) ^ ssw)) = cvt8(a, b);
    *(bf16x8*)((char*)xs + ((sbase + 16) ^ ssw)) = cvt8(c, d);
  }
  __syncthreads();  // the ONLY barrier

#pragma unroll
  for (int i = 0; i < 2; ++i) {
    const int lrow = i * 16 + xrow;
    bf16x8 xf[8];
#pragma unroll
    for (int ks = 0; ks < 8; ++ks)
      xf[ks] = *(const bf16x8*)((const char*)xs +
                                ((lrow * 512 + ks * 64 + g4 * 16) ^ rsw));

#pragma unroll
    for (int ct = 0; ct < 2; ++ct) {
      f32x4 acc = {0.f, 0.f, 0.f, 0.f};
#pragma unroll
      for (int ks = 0; ks < 8; ++ks)
        acc = __builtin_amdgcn_mfma_f32_16x16x32_bf16(af[ct][ks], xf[ks], acc, 0, 0, 0);
      const int ocol = w * 32 + ct * 16 + g4 * 4;
      bf16x4 xr4 = *(const bf16x4*)((const char*)xs +
                                    ((lrow * 512 + ocol * 2) ^ rsw));
      f32x4 xres;
#pragma unroll
      for (int j = 0; j < 4; ++j) xres[j] = (float)xr4[j];
      *(f32x4*)(out + (size_t)(Rbase + i * 16 + xrow) * DD + ocol) =
          acc + xres + bias[ct];
    }
  }
}

extern "C" void kernel_launch(void* const* d_in, const int* in_sizes, int n_in,
                              void* d_out, int out_size, void* d_ws, size_t ws_size,
                              hipStream_t stream) {
  const float* x = (const float*)d_in[0];
  const float* Wqkv = (const float*)d_in[1];
  const float* bqkv = (const float*)d_in[2];
  const float* Wout = (const float*)d_in[3];
  const float* bout = (const float*)d_in[4];
  float* out = (float*)d_out;

  __bf16* Wc = (__bf16*)d_ws;                                   // 128 KiB
  float* bc = (float*)((char*)d_ws + DD * DD * sizeof(__bf16)); // +1 KiB

  wc_bc_kernel<<<DD, 1024, 0, stream>>>(Wqkv, bqkv, Wout, bout, Wc, bc);
  knn_attn_main<<<NROWS / 32, 512, 0, stream>>>(x, Wc, bc, out);
}